// Round 7
// baseline (205.652 us; speedup 1.0000x reference)
//
#include <hip/hip_runtime.h>
#include <stdint.h>

// GCN 2-layer: out = drop(relu(A_hat * (drop(relu((A_hat*X)*W1+b1)) * W2) + b2))
// v8: k_gemm12 rescheduled: 4 waves, A/H frags in registers, K-step 64 dbuf with
//     counted vmcnt(8), bias preloaded (no VMEM in pipeline), 32 phases. Rest = v7.

#define C_IN 256
#define C_HID 512
#define C_OUT 256

typedef unsigned short ushort_t;
typedef __bf16 bf16x8 __attribute__((ext_vector_type(8)));
typedef float floatx4 __attribute__((ext_vector_type(4)));

typedef __attribute__((address_space(1))) const void g1_void;
typedef __attribute__((address_space(3))) void l3_void;

__device__ __forceinline__ void gll16(const ushort_t* g, ushort_t* l) {
  __builtin_amdgcn_global_load_lds((g1_void*)g, (l3_void*)l, 16, 0, 0);
}

// ---------------- Threefry-2x32 (matches JAX) ----------------
__host__ __device__ __forceinline__ void tf_rounds(unsigned& x0, unsigned& x1,
                                                   unsigned k0, unsigned k1) {
  unsigned k2 = k0 ^ k1 ^ 0x1BD11BDAu;
#define ROT(r) { x0 += x1; x1 = (x1 << r) | (x1 >> (32 - r)); x1 ^= x0; }
  x0 += k0; x1 += k1;
  ROT(13) ROT(15) ROT(26) ROT(6)
  x0 += k1; x1 += k2 + 1u;
  ROT(17) ROT(29) ROT(16) ROT(24)
  x0 += k2; x1 += k0 + 2u;
  ROT(13) ROT(15) ROT(26) ROT(6)
  x0 += k0; x1 += k1 + 3u;
  ROT(17) ROT(29) ROT(16) ROT(24)
  x0 += k1; x1 += k2 + 4u;
  ROT(13) ROT(15) ROT(26) ROT(6)
  x0 += k2; x1 += k0 + 5u;
#undef ROT
}

__device__ __forceinline__ float drop_scale(unsigned j, unsigned k0, unsigned k1) {
  unsigned x0 = 0u, x1 = j;
  tf_rounds(x0, x1, k0, k1);
  unsigned bits = x0 ^ x1;
  float u = __uint_as_float((bits >> 9) | 0x3f800000u) - 1.0f;
  return (u < 0.5f) ? 2.0f : 0.0f;
}

// bf16 helpers (RNE)
__device__ __forceinline__ ushort_t f2bf(float f) {
  unsigned u = __float_as_uint(f);
  unsigned r = (u + 0x7fffu + ((u >> 16) & 1u)) >> 16;
  return (ushort_t)r;
}
__device__ __forceinline__ float bf2f(ushort_t h) {
  return __uint_as_float(((unsigned)h) << 16);
}

// ---------------- fused setup: zero cnt | detect dtype | weight convert ----
__global__ __launch_bounds__(256) void k_setup(const unsigned* __restrict__ raw,
                                               unsigned* __restrict__ flag,
                                               int* __restrict__ cnt, int N, int NB,
                                               const float* __restrict__ W1,
                                               const float* __restrict__ W2,
                                               ushort_t* __restrict__ h1,
                                               ushort_t* __restrict__ l1,
                                               ushort_t* __restrict__ h2,
                                               ushort_t* __restrict__ l2) {
  int b = blockIdx.x, t = threadIdx.x;
  if (b < NB) {
    int i = b * 256 + t;
    if (i < N) cnt[i] = 0;
    return;
  }
  if (b == NB) {
    __shared__ unsigned sh[256];
    unsigned acc = 0;
    for (int i = 1 + 2 * t; i < 8192; i += 512) acc |= raw[i];
    sh[t] = acc;
    __syncthreads();
    for (int s = 128; s > 0; s >>= 1) {
      if (t < s) sh[t] |= sh[t + s];
      __syncthreads();
    }
    if (t == 0) *flag = (sh[0] == 0u) ? 1u : 0u;  // 1 => int64
    return;
  }
  int idx = (b - NB - 1) * 256 + t;
  const int S1 = C_IN * C_HID;
  if (idx >= S1 + C_HID * C_OUT) return;
  const float* W; ushort_t *hi, *lo; int K, Nn, li;
  if (idx < S1) { W = W1; hi = h1; lo = l1; K = C_IN; Nn = C_HID; li = idx; }
  else { W = W2; hi = h2; lo = l2; K = C_HID; Nn = C_OUT; li = idx - S1; }
  int k = li / Nn, n = li - k * Nn;
  float v = W[li];
  ushort_t h = f2bf(v);
  hi[(size_t)n * K + k] = h;
  lo[(size_t)n * K + k] = f2bf(v - bf2f(h));
}

// dst-degree histogram straight from raw edges (cnt pre-zeroed)
__global__ __launch_bounds__(256) void k_hist(const void* __restrict__ raw,
                                              const unsigned* __restrict__ flag,
                                              int* __restrict__ cnt, int E) {
  int e = blockIdx.x * 256 + threadIdx.x;
  if (e >= E) return;
  int d;
  if (*flag) d = (int)((const long long*)raw)[E + e];
  else       d = ((const int*)raw)[E + e];
  atomicAdd(&cnt[d], 1);
}

// ---------------- single-block scan: 16 waves, shfl-based ----------------
__global__ __launch_bounds__(1024) void k_scan(const int* __restrict__ cnt,
                                               int* __restrict__ roff,
                                               int* __restrict__ cursor,
                                               float* __restrict__ dinv,
                                               int n, int E) {
  __shared__ int wsum[16];
  __shared__ int sbase;
  int t = threadIdx.x;
  int lane = t & 63, w = t >> 6;
  if (t == 0) sbase = 0;
  __syncthreads();
  for (int c0 = 0; c0 < n; c0 += 1024) {
    int i = c0 + t;
    int v = (i < n) ? cnt[i] : 0;
    int sc = v;
#pragma unroll
    for (int d = 1; d < 64; d <<= 1) {
      int u = __shfl_up(sc, d);
      if (lane >= d) sc += u;
    }
    if (lane == 63) wsum[w] = sc;
    __syncthreads();
    int wpre = 0;
#pragma unroll
    for (int k = 0; k < 16; ++k) wpre += (k < w) ? wsum[k] : 0;
    int base = sbase;
    if (i < n) {
      int excl = base + wpre + sc - v;
      roff[i] = excl;
      cursor[i] = excl;
      dinv[i] = rsqrtf((float)(v + 1));
    }
    __syncthreads();
    if (t == 1023) sbase = base + wpre + sc;
    __syncthreads();
  }
  if (t == 0) roff[n] = E;
}

__global__ __launch_bounds__(256) void k_scatter(const void* __restrict__ raw,
                                                 const unsigned* __restrict__ flag,
                                                 int* __restrict__ cursor,
                                                 int* __restrict__ csr, int E) {
  int e = blockIdx.x * 256 + threadIdx.x;
  if (e >= E) return;
  int s, d;
  if (*flag) {
    s = (int)((const long long*)raw)[e];
    d = (int)((const long long*)raw)[E + e];
  } else {
    s = ((const int*)raw)[e];
    d = ((const int*)raw)[E + e];
  }
  int slot = atomicAdd(&cursor[d], 1);
  csr[slot] = s;
}

// ---------------- gather: 4 nodes/block, csr-prefetch dbuf, unroll-8 --------
template <int EPI, int PRE>
__global__ __launch_bounds__(256) void k_gather4(const int* __restrict__ roff,
                                                 const int* __restrict__ csr,
                                                 const float* __restrict__ dinv,
                                                 const float* __restrict__ x,
                                                 const float* __restrict__ bias,
                                                 void* __restrict__ o1,
                                                 void* __restrict__ o2,
                                                 unsigned dk0, unsigned dk1) {
  int g = threadIdx.x >> 6;
  int tg = threadIdx.x & 63;
  int node = blockIdx.x * 4 + g;
  float dd = dinv[node];
  const float4* xr = (const float4*)x;
  float4 v = xr[(size_t)node * 64 + tg];
  float4 acc;
  if (PRE) acc = v;
  else acc = make_float4(dd * v.x, dd * v.y, dd * v.z, dd * v.w);
  int p = roff[node], end = roff[node + 1];
  int s[8];
  bool have = (p + 8 <= end);
  if (have) {
#pragma unroll
    for (int q = 0; q < 8; ++q) s[q] = csr[p + q];
  }
  while (have) {
    int sn[8];
    bool haven = (p + 16 <= end);
    if (haven) {
#pragma unroll
      for (int q = 0; q < 8; ++q) sn[q] = csr[p + 8 + q];
    }
    float4 r[8];
#pragma unroll
    for (int q = 0; q < 8; ++q) r[q] = xr[(size_t)s[q] * 64 + tg];
    if (PRE) {
#pragma unroll
      for (int q = 0; q < 8; ++q) {
        acc.x += r[q].x; acc.y += r[q].y; acc.z += r[q].z; acc.w += r[q].w;
      }
    } else {
      float w[8];
#pragma unroll
      for (int q = 0; q < 8; ++q) w[q] = dinv[s[q]];
#pragma unroll
      for (int q = 0; q < 8; ++q) {
        acc.x += w[q] * r[q].x; acc.y += w[q] * r[q].y;
        acc.z += w[q] * r[q].z; acc.w += w[q] * r[q].w;
      }
    }
    p += 8;
#pragma unroll
    for (int q = 0; q < 8; ++q) s[q] = sn[q];
    have = haven;
  }
  for (; p + 4 <= end; p += 4) {
    int s0 = csr[p], s1 = csr[p + 1], s2 = csr[p + 2], s3 = csr[p + 3];
    float4 a = xr[(size_t)s0 * 64 + tg];
    float4 b = xr[(size_t)s1 * 64 + tg];
    float4 c = xr[(size_t)s2 * 64 + tg];
    float4 d = xr[(size_t)s3 * 64 + tg];
    if (PRE) {
      acc.x += a.x + b.x + c.x + d.x;
      acc.y += a.y + b.y + c.y + d.y;
      acc.z += a.z + b.z + c.z + d.z;
      acc.w += a.w + b.w + c.w + d.w;
    } else {
      float w0 = dinv[s0], w1 = dinv[s1], w2 = dinv[s2], w3 = dinv[s3];
      acc.x += w0 * a.x + w1 * b.x + w2 * c.x + w3 * d.x;
      acc.y += w0 * a.y + w1 * b.y + w2 * c.y + w3 * d.y;
      acc.z += w0 * a.z + w1 * b.z + w2 * c.z + w3 * d.z;
      acc.w += w0 * a.w + w1 * b.w + w2 * c.w + w3 * d.w;
    }
  }
  for (; p < end; ++p) {
    int s0 = csr[p];
    float4 a = xr[(size_t)s0 * 64 + tg];
    if (PRE) {
      acc.x += a.x; acc.y += a.y; acc.z += a.z; acc.w += a.w;
    } else {
      float w0 = dinv[s0];
      acc.x += w0 * a.x; acc.y += w0 * a.y; acc.z += w0 * a.z; acc.w += w0 * a.w;
    }
  }
  acc.x *= dd; acc.y *= dd; acc.z *= dd; acc.w *= dd;
  if (EPI) {
    float4 bb = ((const float4*)bias)[tg];
    acc.x = fmaxf(acc.x + bb.x, 0.0f);
    acc.y = fmaxf(acc.y + bb.y, 0.0f);
    acc.z = fmaxf(acc.z + bb.z, 0.0f);
    acc.w = fmaxf(acc.w + bb.w, 0.0f);
    unsigned jb = (unsigned)node * 256u + (unsigned)tg * 4u;
    acc.x *= drop_scale(jb + 0u, dk0, dk1);
    acc.y *= drop_scale(jb + 1u, dk0, dk1);
    acc.z *= drop_scale(jb + 2u, dk0, dk1);
    acc.w *= drop_scale(jb + 3u, dk0, dk1);
    ((float4*)o1)[(size_t)node * 64 + tg] = acc;
  } else {
    ushort_t h0 = f2bf(acc.x), h1 = f2bf(acc.y), h2 = f2bf(acc.z), h3 = f2bf(acc.w);
    ushort4 hv = make_ushort4(h0, h1, h2, h3);
    ushort4 lv = make_ushort4(f2bf(acc.x - bf2f(h0)), f2bf(acc.y - bf2f(h1)),
                              f2bf(acc.z - bf2f(h2)), f2bf(acc.w - bf2f(h3)));
    ((ushort4*)o1)[(size_t)node * 64 + tg] = hv;
    ((ushort4*)o2)[(size_t)node * 64 + tg] = lv;
  }
}

// ---------------- fused gemm1+gemm2 v2: 4 waves, A/H in regs, K-step 64 -----
// 256 thr, 32-row slabs, grid 313, 2 blocks/CU (80KB LDS).
// Per cb: 4 G1 phases (K64, W1 tile dbuf) -> H1 epilogue to sH -> H frags to regs
// -> 4 G2 phases. Counted vmcnt(8); bias preloaded (no VMEM inside pipeline).
__global__ __launch_bounds__(256, 2) void k_gemm12(
    const ushort_t* __restrict__ Ahi, const ushort_t* __restrict__ Alo,
    const ushort_t* __restrict__ B1h, const ushort_t* __restrict__ B1l,
    const ushort_t* __restrict__ B2h, const ushort_t* __restrict__ B2l,
    const float* __restrict__ b1, const float* __restrict__ dinv,
    float* __restrict__ hw2, int M, unsigned dk0, unsigned dk1) {
  __shared__ __attribute__((aligned(16))) ushort_t sBh[2][8192], sBl[2][8192];
  __shared__ __attribute__((aligned(16))) ushort_t sHh[4096], sHl[4096];
  const int t = threadIdx.x;
  const int lane = t & 63, wave = t >> 6;       // 4 waves
  const int wm = wave & 1, wn = wave >> 1;      // rows 2x16 / cols 2x64
  const int quad = lane >> 4, l16 = lane & 15;
  const int row0 = blockIdx.x * 32;
  const int rA = wm * 16 + l16;                 // A/H fragment row (0..31)

  // ---- prologue: A frags + bias to registers (complete before pipeline) ----
  bf16x8 Ah[8], Al[8];
  {
    const int ga = min(row0 + rA, M - 1);
    const ushort_t* pa = Ahi + (size_t)ga * 256 + quad * 8;
    const ushort_t* pl = Alo + (size_t)ga * 256 + quad * 8;
#pragma unroll
    for (int k8 = 0; k8 < 8; ++k8) {
      Ah[k8] = *(const bf16x8*)(pa + k8 * 32);
      Al[k8] = *(const bf16x8*)(pl + k8 * 32);
    }
  }
  float bpre[4][4];
#pragma unroll
  for (int cb = 0; cb < 4; ++cb)
#pragma unroll
    for (int j = 0; j < 4; ++j)
      bpre[cb][j] = b1[cb * 128 + wn * 64 + j * 16 + l16];
#pragma unroll
  for (int k8 = 0; k8 < 8; ++k8)
    asm volatile("" :: "v"(Ah[k8]), "v"(Al[k8]));
#pragma unroll
  for (int cb = 0; cb < 4; ++cb)
    asm volatile("" :: "v"(bpre[cb][0]), "v"(bpre[cb][1]),
                       "v"(bpre[cb][2]), "v"(bpre[cb][3]));

  // stage a 128-row x 64-K tile (hi+lo): 16 slabs of 8 rows, 4 slabs/wave.
  // dest linear (slab*512 + lane*8); source k-chunk pre-swizzled ^(row&7).
#define STG(bh_, bl_, Kd_, colb_, kb_, c_) {                                   \
    _Pragma("unroll")                                                          \
    for (int i_ = 0; i_ < 4; ++i_) {                                           \
      int slab_ = wave * 4 + i_;                                               \
      int row_ = slab_ * 8 + (lane >> 3);                                      \
      int kch_ = (((lane & 7) ^ (row_ & 7)) * 8);                              \
      gll16(bh_ + (size_t)(colb_ + row_) * Kd_ + (kb_) + kch_,                 \
            &sBh[c_][slab_ * 512]);                                            \
      gll16(bl_ + (size_t)(colb_ + row_) * Kd_ + (kb_) + kch_,                 \
            &sBl[c_][slab_ * 512]);                                            \
    } }

  STG(B1h, B1l, 256, 0, 0, 0)
  asm volatile("s_waitcnt vmcnt(0)\n\ts_barrier" ::: "memory");

  floatx4 acc2[2][4] = {};
  int c = 0;
  for (int cb = 0; cb < 4; ++cb) {
    floatx4 acc1[4] = {};
    // ---- gemm1: 4 phases x K64 ----
#pragma unroll
    for (int k2 = 0; k2 < 4; ++k2) {
      if (k2 < 3) { STG(B1h, B1l, 256, cb * 128, (k2 + 1) * 64, c ^ 1) }
      else        { STG(B2h, B2l, 512, 0, cb * 128, c ^ 1) }
      asm volatile("s_waitcnt vmcnt(8)\n\ts_barrier" ::: "memory");
#pragma unroll
      for (int kk = 0; kk < 2; ++kk) {
        bf16x8 ah = Ah[k2 * 2 + kk], al = Al[k2 * 2 + kk];
#pragma unroll
        for (int j = 0; j < 4; ++j) {
          int rb = wn * 64 + j * 16 + l16;
          int ob = rb * 64 + (((kk * 4 + quad) ^ (rb & 7)) * 8);
          bf16x8 bh = *(const bf16x8*)&sBh[c][ob];
          bf16x8 bl = *(const bf16x8*)&sBl[c][ob];
          acc1[j] = __builtin_amdgcn_mfma_f32_16x16x32_bf16(ah, bh, acc1[j], 0, 0, 0);
          acc1[j] = __builtin_amdgcn_mfma_f32_16x16x32_bf16(ah, bl, acc1[j], 0, 0, 0);
          acc1[j] = __builtin_amdgcn_mfma_f32_16x16x32_bf16(al, bh, acc1[j], 0, 0, 0);
        }
      }
      asm volatile("s_barrier" ::: "memory");
      c ^= 1;
    }
    // ---- H1 epilogue -> sH (bias, relu, dropout, bf16 hi/lo split) ----
#pragma unroll
    for (int j = 0; j < 4; ++j) {
      int kc = wn * 64 + j * 16 + l16;    // col in tile 0..127
      int gc = cb * 128 + kc;
      float bb = bpre[cb][j];
#pragma unroll
      for (int reg = 0; reg < 4; ++reg) {
        int row = wm * 16 + quad * 4 + reg;
        float v = fmaxf(acc1[j][reg] + bb, 0.0f);
        v *= drop_scale((unsigned)(row0 + row) * 512u + (unsigned)gc, dk0, dk1);
        ushort_t h = f2bf(v);
        int idx = row * 128 + (((kc >> 3) ^ (row & 7)) * 8) + (kc & 7);
        sHh[idx] = h;
        sHl[idx] = f2bf(v - bf2f(h));
      }
    }
    asm volatile("s_waitcnt lgkmcnt(0)\n\ts_barrier" ::: "memory");
    // H fragments to registers (4 k-chunks x hi/lo)
    bf16x8 hh[4], hl[4];
#pragma unroll
    for (int kc2 = 0; kc2 < 4; ++kc2) {
      int oh = rA * 128 + (((kc2 * 4 + quad) ^ (rA & 7)) * 8);
      hh[kc2] = *(const bf16x8*)&sHh[oh];
      hl[kc2] = *(const bf16x8*)&sHl[oh];
    }
    // ---- gemm2: 4 phases (2 col-phases x 2 K64-steps) ----
#pragma unroll
    for (int s2 = 0; s2 < 4; ++s2) {
      const int ph = s2 >> 1, kk2 = s2 & 1;
      bool staged = true;
      if (s2 < 3) {
        const int sn = s2 + 1;
        STG(B2h, B2l, 512, (sn >> 1) * 128, cb * 128 + (sn & 1) * 64, c ^ 1)
      } else if (cb < 3) {
        STG(B1h, B1l, 256, (cb + 1) * 128, 0, c ^ 1)
      } else {
        staged = false;
      }
      if (staged) asm volatile("s_waitcnt vmcnt(8)\n\ts_barrier" ::: "memory");
      else        asm volatile("s_waitcnt vmcnt(0)\n\ts_barrier" ::: "memory");
#pragma unroll
      for (int kk = 0; kk < 2; ++kk) {
        bf16x8 ah = hh[kk2 * 2 + kk], al = hl[kk2 * 2 + kk];
#pragma unroll
        for (int j = 0; j < 4; ++j) {
          int rb = wn * 64 + j * 16 + l16;
          int ob = rb * 64 + (((kk * 4 + quad) ^ (rb & 7)) * 8);
          bf16x8 bh = *(const bf16x8*)&sBh[c][ob];
          bf16x8 bl = *(const bf16x8*)&sBl[c][ob];
          acc2[ph][j] = __builtin_amdgcn_mfma_f32_16x16x32_bf16(ah, bh, acc2[ph][j], 0, 0, 0);
          acc2[ph][j] = __builtin_amdgcn_mfma_f32_16x16x32_bf16(ah, bl, acc2[ph][j], 0, 0, 0);
          acc2[ph][j] = __builtin_amdgcn_mfma_f32_16x16x32_bf16(al, bh, acc2[ph][j], 0, 0, 0);
        }
      }
      asm volatile("s_barrier" ::: "memory");
      c ^= 1;
    }
  }
#undef STG
  // ---- final epilogue: hw2 = acc2 * dinv[row] (row-prescale for gather2) ----
#pragma unroll
  for (int ph = 0; ph < 2; ++ph) {
#pragma unroll
    for (int j = 0; j < 4; ++j) {
      int gc = ph * 128 + wn * 64 + j * 16 + l16;
#pragma unroll
      for (int reg = 0; reg < 4; ++reg) {
        int gr = row0 + wm * 16 + quad * 4 + reg;
        if (gr < M) hw2[(size_t)gr * 256 + gc] = acc2[ph][j][reg] * dinv[gr];
      }
    }
  }
}

extern "C" void kernel_launch(void* const* d_in, const int* in_sizes, int n_in,
                              void* d_out, int out_size, void* d_ws, size_t ws_size,
                              hipStream_t stream) {
  const float* x  = (const float*)d_in[0];
  const void*  ei = d_in[1];
  const float* W1 = (const float*)d_in[2];
  const float* b1 = (const float*)d_in[3];
  const float* W2 = (const float*)d_in[4];
  const float* b2 = (const float*)d_in[5];
  float* out = (float*)d_out;

  const int N = in_sizes[0] / C_IN;   // 10000
  const int E = in_sizes[1] / 2;      // 160000
  const int NB = (N + 255) / 256;     // 40

  unsigned a0 = 0u, a1 = 0u, b0 = 0u, b1k = 1u;
  tf_rounds(a0, a1, 0u, 42u);   // dk1
  tf_rounds(b0, b1k, 0u, 42u);  // dk2

  uintptr_t base = (uintptr_t)d_ws;
  unsigned*  flag   = (unsigned*)base;
  int*       cnt    = (int*)(base + 16 * 1024);
  int*       roff   = (int*)(base + 64 * 1024);
  int*       cursor = (int*)(base + 128 * 1024);
  float*     dinv   = (float*)(base + 192 * 1024);
  int*       csr    = (int*)(base + 2u * 1024 * 1024);
  ushort_t*  Ahi    = (ushort_t*)(base + 4u  * 1024 * 1024);
  ushort_t*  Alo    = (ushort_t*)(base + 10u * 1024 * 1024);
  float*     hw2    = (float*)(base + 38u * 1024 * 1024);
  ushort_t*  W1thi  = (ushort_t*)(base + 49u * 1024 * 1024);
  ushort_t*  W1tlo  = (ushort_t*)(base + 49u * 1024 * 1024 + 512 * 1024);
  ushort_t*  W2thi  = (ushort_t*)(base + 50u * 1024 * 1024);
  ushort_t*  W2tlo  = (ushort_t*)(base + 50u * 1024 * 1024 + 512 * 1024);

  dim3 b256(256);
  const int WCB = (C_IN * C_HID + C_HID * C_OUT + 255) / 256;

  // 1. fused setup: zero cnt | detect | weight convert
  k_setup<<<dim3(NB + 1 + WCB), b256, 0, stream>>>((const unsigned*)ei, flag, cnt,
                                                   N, NB, W1, W2,
                                                   W1thi, W1tlo, W2thi, W2tlo);
  // 2. degree histogram
  k_hist<<<dim3((E + 255) / 256), b256, 0, stream>>>(ei, flag, cnt, E);
  // 3. single-block scan
  k_scan<<<dim3(1), dim3(1024), 0, stream>>>(cnt, roff, cursor, dinv, N, E);
  // 4. CSR scatter
  k_scatter<<<dim3((E + 255) / 256), b256, 0, stream>>>(ei, flag, cursor, csr, E);
  // 5. layer-1 aggregate (full-TLP gather) -> bf16 split A
  k_gather4<0, 0><<<dim3(N / 4), b256, 0, stream>>>(roff, csr, dinv, x, nullptr,
                                                    Ahi, Alo, 0u, 0u);
  // 6. fused gemm1+gemm2 -> hw2 (row-prescaled); H1 never leaves LDS
  k_gemm12<<<dim3((N + 31) / 32), b256, 0, stream>>>(
      Ahi, Alo, W1thi, W1tlo, W2thi, W2tlo, b1, dinv, hw2, N, a0, a1);
  // 7. out = drop(relu(dd * (sum hw2'[nbrs] + hw2'[self]) + b2))
  k_gather4<1, 1><<<dim3(N / 4), b256, 0, stream>>>(roff, csr, dinv, hw2, b2,
                                                    out, nullptr, b0, b1k);
}